// Round 5
// baseline (100.210 us; speedup 1.0000x reference)
//
#include <hip/hip_runtime.h>

typedef __attribute__((ext_vector_type(8))) short bf16x8;
typedef __attribute__((ext_vector_type(4))) float f32x4;
typedef __attribute__((ext_vector_type(4), aligned(4))) float f32x4u;  // 4B-aligned vector load

#define LOG2F 0.69314718055994531f

// Problem dims (fixed by harness)
#define NB 16
#define NA 512
#define NN 64
#define NG 25
#define NF 128

__device__ __forceinline__ unsigned short f2bf(float x) {
    __bf16 h = (__bf16)x;                       // hw v_cvt (RNE), pairs to v_cvt_pk_bf16_f32
    return __builtin_bit_cast(unsigned short, h);
}
__device__ __forceinline__ float bf2f(unsigned short h) {
    union { unsigned int u; float f; } c; c.u = ((unsigned int)h) << 16;
    return c.f;
}
__device__ __forceinline__ float sspf(float x) {
    // |x| bounded (~<10) in this net: no overflow guard needed
    return __logf(1.0f + __expf(x)) - LOG2F;
}

// ws fragment layout (ushort units):
//   [0,      4096)  Wf1^T A-frags : [tc=8][lane=64][j=8]   A of 16x16x32: row=f1=tc*16+(l&15), k=g=(l>>4)*8+j
//   [4096,  20480)  Wf2   B-frags : [tn=8][ks=4][lane][8]  B: col=f=tn*16+(l&15), k=ks*32+(l>>4)*8+j
//   [20480, 36864)  W_in2f B-frags: same shape
//   [36864, 53248)  W_out  B-frags: same shape
#define FRAG_WF1 0
#define FRAG_WF2 4096
#define FRAG_WIN 20480
#define FRAG_WOUT 36864

__global__ __launch_bounds__(256) void k_prep(
    const float* __restrict__ Wf1, const float* __restrict__ Wf2,
    const float* __restrict__ Win, const float* __restrict__ Wout,
    unsigned short* __restrict__ frag)
{
    int idx = blockIdx.x * 256 + threadIdx.x;
    if (idx < 4096) {
        int j = idx & 7, lane = (idx >> 3) & 63, tc = idx >> 9;
        int f1 = tc * 16 + (lane & 15);
        int g  = (lane >> 4) * 8 + j;
        frag[idx] = (g < NG) ? f2bf(Wf1[g * NF + f1]) : (unsigned short)0;
    } else if (idx < 20480) {
        int t = idx - 4096;
        int j = t & 7, lane = (t >> 3) & 63, ks = (t >> 9) & 3, tn = t >> 11;
        int f = tn * 16 + (lane & 15);
        int k = ks * 32 + (lane >> 4) * 8 + j;
        frag[idx] = f2bf(Wf2[k * NF + f]);
    } else if (idx < 36864) {
        int t = idx - 20480;
        int j = t & 7, lane = (t >> 3) & 63, ks = (t >> 9) & 3, tn = t >> 11;
        int f = tn * 16 + (lane & 15);
        int k = ks * 32 + (lane >> 4) * 8 + j;
        frag[idx] = f2bf(Win[k * NF + f]);
    } else if (idx < 53248) {
        int t = idx - 36864;
        int j = t & 7, lane = (t >> 3) & 63, ks = (t >> 9) & 3, tn = t >> 11;
        int f = tn * 16 + (lane & 15);
        int k = ks * 32 + (lane >> 4) * 8 + j;
        frag[idx] = f2bf(Wout[k * NF + f]);
    }
}

// y = x @ W_in2f  -> bf16, rows = NB*NA = 8192, BM=32 per block (256 blocks)
__global__ __launch_bounds__(256) void k_in2f(
    const float* __restrict__ x, const unsigned short* __restrict__ frag,
    unsigned short* __restrict__ ybf)
{
    const unsigned short* winfrag = frag + FRAG_WIN;
    const int lane = threadIdx.x & 63, w = threadIdx.x >> 6;
    const int rowbase = blockIdx.x * 32;
    f32x4 acc[2][2];
    f32x4 z = {0.f, 0.f, 0.f, 0.f};
    acc[0][0] = z; acc[0][1] = z; acc[1][0] = z; acc[1][1] = z;
#pragma unroll
    for (int ks = 0; ks < 4; ++ks) {
        bf16x8 a[2];
#pragma unroll
        for (int tm = 0; tm < 2; ++tm) {
            int row = rowbase + tm * 16 + (lane & 15);
            int k0  = ks * 32 + (lane >> 4) * 8;
            const float* p = x + (size_t)row * NF + k0;
            float4 v0 = *(const float4*)p;
            float4 v1 = *(const float4*)(p + 4);
            bf16x8 t;
            t[0] = (short)f2bf(v0.x); t[1] = (short)f2bf(v0.y);
            t[2] = (short)f2bf(v0.z); t[3] = (short)f2bf(v0.w);
            t[4] = (short)f2bf(v1.x); t[5] = (short)f2bf(v1.y);
            t[6] = (short)f2bf(v1.z); t[7] = (short)f2bf(v1.w);
            a[tm] = t;
        }
#pragma unroll
        for (int tn = 0; tn < 2; ++tn) {
            bf16x8 bfr = *(const bf16x8*)(winfrag + ((((w * 2 + tn) * 4 + ks) * 64) + lane) * 8);
#pragma unroll
            for (int tm = 0; tm < 2; ++tm)
                acc[tm][tn] = __builtin_amdgcn_mfma_f32_16x16x32_bf16(a[tm], bfr, acc[tm][tn], 0, 0, 0);
        }
    }
#pragma unroll
    for (int tm = 0; tm < 2; ++tm)
#pragma unroll
        for (int tn = 0; tn < 2; ++tn)
#pragma unroll
            for (int r = 0; r < 4; ++r) {
                int row = rowbase + tm * 16 + (lane >> 4) * 4 + r;
                int f   = w * 32 + tn * 16 + (lane & 15);
                ybf[(size_t)row * NF + f] = f2bf(acc[tm][tn][r]);
            }
}

// Fused per-atom kernel: W1 = ssp(fij@Wf1+b1); W = W1@Wf2+b2; agg = sum_n W*mask*y[nbh]
// Single barrier; y read direct from L2 (per-batch slice = 128KB, shared by 512 blocks).
// LDS = 16.9KB -> 8 blocks/CU (occupancy-driven design).
__global__ __launch_bounds__(256, 8) void k_cfconv(
    const float* __restrict__ fij, const int* __restrict__ nbh,
    const float* __restrict__ mask, const float* __restrict__ b1,
    const float* __restrict__ b2, const unsigned short* __restrict__ frag,
    const unsigned short* __restrict__ ybf, float* __restrict__ agg)
{
    __shared__ unsigned short sW1T[64 * 128];  // [n][k] bf16, XOR-swizzled byte^((n&7)<<4)
    __shared__ alignas(16) float smask[64];
    __shared__ alignas(16) int   snbh[64];

    const int tid = threadIdx.x, lane = tid & 63, w = tid >> 6;
    const int g = lane >> 4, lc = lane & 15;
    const int atom = blockIdx.x;
    const int bidx = atom >> 9;

    if (tid < 64) {
        smask[tid] = mask[(size_t)atom * NN + tid];
        snbh[tid]  = nbh[(size_t)atom * NN + tid];
    }

    // ---- step A: W1^T = Wf1^T(128x32) @ fij^T(32x64) + b1; wave owns f1-tiles {2w,2w+1} ----
    // fij B-frags straight from global: col n = tn*16+lc, k = g*8+j.
    // Tail group g==3: only k=24 (j=0) is valid -> scalar load + zero fill (no OOB reads).
    const unsigned short* wf1frag = frag + FRAG_WF1;
    const float* fp = fij + (size_t)atom * (NN * NG);
    bf16x8 afr[2], bfr[4];
#pragma unroll
    for (int i = 0; i < 2; ++i)
        afr[i] = *(const bf16x8*)(wf1frag + (((2 * w + i) * 64) + lane) * 8);
    {
        const int g0 = g * 8;
        const bool tail = (g == 3);
#pragma unroll
        for (int tn = 0; tn < 4; ++tn) {
            int n = tn * 16 + lc;
            const float* p = fp + n * NG + g0;
            bf16x8 t;
            if (tail) {
                float v = p[0];                        // k=24, always in-bounds
                t[0] = (short)f2bf(v);
                t[1] = 0; t[2] = 0; t[3] = 0; t[4] = 0; t[5] = 0; t[6] = 0; t[7] = 0;
            } else {
                f32x4u v0 = *(const f32x4u*)p;         // k=g0..g0+7 <= 23, in-bounds
                f32x4u v1 = *(const f32x4u*)(p + 4);
                t[0] = (short)f2bf(v0[0]); t[1] = (short)f2bf(v0[1]);
                t[2] = (short)f2bf(v0[2]); t[3] = (short)f2bf(v0[3]);
                t[4] = (short)f2bf(v1[0]); t[5] = (short)f2bf(v1[1]);
                t[6] = (short)f2bf(v1[2]); t[7] = (short)f2bf(v1[3]);
            }
            bfr[tn] = t;
        }
    }
    f32x4 dW[2][4];
#pragma unroll
    for (int i = 0; i < 2; ++i) {
        int c0 = (2 * w + i) * 16 + g * 4;
        f32x4 ci = *(const f32x4*)(b1 + c0);            // bias folded into MFMA C-in
#pragma unroll
        for (int tn = 0; tn < 4; ++tn)
            dW[i][tn] = __builtin_amdgcn_mfma_f32_16x16x32_bf16(afr[i], bfr[tn], ci, 0, 0, 0);
    }

    // ssp + pack -> swizzled LDS (D-frag: col n = lane&15, rows c = c0+reg, 4 contiguous)
#pragma unroll
    for (int i = 0; i < 2; ++i) {
        int c0 = (2 * w + i) * 16 + g * 4;
#pragma unroll
        for (int tn = 0; tn < 4; ++tn) {
            int n = tn * 16 + lc;
            ushort4 pk;
#pragma unroll
            for (int r = 0; r < 4; ++r)
                ((unsigned short*)&pk)[r] = f2bf(sspf(dW[i][tn][r]));
            *(ushort4*)((char*)sW1T + n * 256 + ((c0 * 2) ^ ((n & 7) << 4))) = pk;
        }
    }
    __syncthreads();

    // ---- step B: W = W1(64x128) @ Wf2(128x128) + b2; wave f-slice [w*32, w*32+32) ----
    const unsigned short* wf2frag = frag + FRAG_WF2;
    const int fbase = w * 32;
    const int fc0 = fbase + lc;
    const float bias0 = b2[fc0], bias1 = b2[fc0 + 16];
    f32x4 acc[4][2];
#pragma unroll
    for (int tm = 0; tm < 4; ++tm) {
        acc[tm][0] = f32x4{bias0, bias0, bias0, bias0};  // b2 folded into C-in
        acc[tm][1] = f32x4{bias1, bias1, bias1, bias1};
    }
#pragma unroll
    for (int ks = 0; ks < 4; ++ks) {
        bf16x8 a4[4];
#pragma unroll
        for (int tm = 0; tm < 4; ++tm) {
            int n  = tm * 16 + lc;
            int kb = ks * 64 + g * 16;             // byte offset of k0*2
            a4[tm] = *(const bf16x8*)((char*)sW1T + n * 256 + (kb ^ ((n & 7) << 4)));
        }
#pragma unroll
        for (int tnl = 0; tnl < 2; ++tnl) {
            int tn = w * 2 + tnl;
            bf16x8 bf2 = *(const bf16x8*)(wf2frag + (((tn * 4 + ks) * 64) + lane) * 8);
#pragma unroll
            for (int tm = 0; tm < 4; ++tm)
                acc[tm][tnl] = __builtin_amdgcn_mfma_f32_16x16x32_bf16(a4[tm], bf2, acc[tm][tnl], 0, 0, 0);
        }
    }

    // ---- step C: agg[f] = sum_n W[n][f] * mask[n] * y[b, nbh[n], f] ----
    // y read direct from global (L2-hot 128KB batch slice); 2 u16 loads share one vaddr
    // (offset 0 / +32B immediate). n per thread: g*4 + tm*16 + r (16 rows).
    float aggv0 = 0.f, aggv1 = 0.f;
    const unsigned short* yb = ybf + (size_t)bidx * NA * NF;
#pragma unroll
    for (int tm = 0; tm < 4; ++tm) {
        f32x4 m4 = *(const f32x4*)(smask + tm * 16 + g * 4);
        int4  nb4 = *(const int4*)(snbh + tm * 16 + g * 4);
#pragma unroll
        for (int r = 0; r < 4; ++r) {
            int yrow = (r == 0) ? nb4.x : (r == 1) ? nb4.y : (r == 2) ? nb4.z : nb4.w;
            const unsigned short* yp = yb + (size_t)yrow * NF + fc0;
            float y0 = bf2f(yp[0]);
            float y1 = bf2f(yp[16]);
            aggv0 = fmaf(acc[tm][0][r] * m4[r], y0, aggv0);
            aggv1 = fmaf(acc[tm][1][r] * m4[r], y1, aggv1);
        }
    }
    aggv0 += __shfl_xor(aggv0, 16); aggv1 += __shfl_xor(aggv1, 16);
    aggv0 += __shfl_xor(aggv0, 32); aggv1 += __shfl_xor(aggv1, 32);
    if (lane < 16) {
        float* ap = agg + (size_t)atom * NF + fbase;
        ap[lane] = aggv0;
        ap[16 + lane] = aggv1;
    }
}

// out = ssp(agg @ W_out + b_out), rows = 8192, BM=32 (256 blocks)
__global__ __launch_bounds__(256) void k_out(
    const float* __restrict__ agg, const unsigned short* __restrict__ frag,
    const float* __restrict__ bout, float* __restrict__ out)
{
    const unsigned short* wofrag = frag + FRAG_WOUT;
    const int lane = threadIdx.x & 63, w = threadIdx.x >> 6;
    const int rowbase = blockIdx.x * 32;
    const int f0 = w * 32 + (lane & 15);
    const float bo0 = bout[f0], bo1 = bout[f0 + 16];
    f32x4 acc[2][2];
    acc[0][0] = f32x4{bo0, bo0, bo0, bo0};
    acc[1][0] = f32x4{bo0, bo0, bo0, bo0};
    acc[0][1] = f32x4{bo1, bo1, bo1, bo1};
    acc[1][1] = f32x4{bo1, bo1, bo1, bo1};
#pragma unroll
    for (int ks = 0; ks < 4; ++ks) {
        bf16x8 a[2];
#pragma unroll
        for (int tm = 0; tm < 2; ++tm) {
            int row = rowbase + tm * 16 + (lane & 15);
            int k0  = ks * 32 + (lane >> 4) * 8;
            const float* p = agg + (size_t)row * NF + k0;
            float4 v0 = *(const float4*)p;
            float4 v1 = *(const float4*)(p + 4);
            bf16x8 t;
            t[0] = (short)f2bf(v0.x); t[1] = (short)f2bf(v0.y);
            t[2] = (short)f2bf(v0.z); t[3] = (short)f2bf(v0.w);
            t[4] = (short)f2bf(v1.x); t[5] = (short)f2bf(v1.y);
            t[6] = (short)f2bf(v1.z); t[7] = (short)f2bf(v1.w);
            a[tm] = t;
        }
#pragma unroll
        for (int tn = 0; tn < 2; ++tn) {
            bf16x8 bfr = *(const bf16x8*)(wofrag + ((((w * 2 + tn) * 4 + ks) * 64) + lane) * 8);
#pragma unroll
            for (int tm = 0; tm < 2; ++tm)
                acc[tm][tn] = __builtin_amdgcn_mfma_f32_16x16x32_bf16(a[tm], bfr, acc[tm][tn], 0, 0, 0);
        }
    }
#pragma unroll
    for (int tm = 0; tm < 2; ++tm)
#pragma unroll
        for (int tn = 0; tn < 2; ++tn)
#pragma unroll
            for (int r = 0; r < 4; ++r) {
                int row = rowbase + tm * 16 + (lane >> 4) * 4 + r;
                int f   = w * 32 + tn * 16 + (lane & 15);
                out[(size_t)row * NF + f] = sspf(acc[tm][tn][r]);
            }
}

extern "C" void kernel_launch(void* const* d_in, const int* in_sizes, int n_in,
                              void* d_out, int out_size, void* d_ws, size_t ws_size,
                              hipStream_t stream)
{
    (void)in_sizes; (void)n_in; (void)out_size; (void)ws_size;
    const float* x    = (const float*)d_in[0];
    // d_in[1] = r_ij (unused by reference)
    const float* fij  = (const float*)d_in[2];
    const int*   nbh  = (const int*)d_in[3];
    const float* mask = (const float*)d_in[4];
    const float* Win  = (const float*)d_in[5];
    const float* Wf1  = (const float*)d_in[6];
    const float* b1   = (const float*)d_in[7];
    const float* Wf2  = (const float*)d_in[8];
    const float* b2   = (const float*)d_in[9];
    const float* Wout = (const float*)d_in[10];
    const float* bout = (const float*)d_in[11];
    float* out = (float*)d_out;

    // ws layout: [0,106496) frags (53248 ushorts) | [106496, +2MB) y bf16 | [2203648, +4MB) agg f32
    unsigned short* frag = (unsigned short*)d_ws;
    unsigned short* ybf  = (unsigned short*)((char*)d_ws + 106496);
    float*          agg  = (float*)((char*)d_ws + 2203648);

    k_prep  <<<208,  256, 0, stream>>>(Wf1, Wf2, Win, Wout, frag);
    k_in2f  <<<256,  256, 0, stream>>>(x, frag, ybf);
    k_cfconv<<<8192, 256, 0, stream>>>(fij, nbh, mask, b1, b2, frag, ybf, agg);
    k_out   <<<256,  256, 0, stream>>>(agg, frag, bout, out);
}

// Round 6
// 75.967 us; speedup vs baseline: 1.3191x; 1.3191x over previous
//
#include <hip/hip_runtime.h>

typedef __attribute__((ext_vector_type(8))) short bf16x8;
typedef __attribute__((ext_vector_type(4))) float f32x4;
typedef __attribute__((ext_vector_type(4), aligned(4))) float f32x4u;  // 4B-aligned vector load

#define LOG2F 0.69314718055994531f

// Problem dims (fixed by harness)
#define NB 16
#define NA 512
#define NN 64
#define NG 25
#define NF 128

__device__ __forceinline__ unsigned short f2bf(float x) {
    __bf16 h = (__bf16)x;                       // hw v_cvt (RNE), pairs to v_cvt_pk_bf16_f32
    return __builtin_bit_cast(unsigned short, h);
}
__device__ __forceinline__ float bf2f(unsigned short h) {
    union { unsigned int u; float f; } c; c.u = ((unsigned int)h) << 16;
    return c.f;
}
__device__ __forceinline__ float sspf(float x) {
    // |x| bounded (~<10) in this net: no overflow guard needed
    return __logf(1.0f + __expf(x)) - LOG2F;
}

// ws fragment layout (ushort units):
//   [0,      4096)  Wf1^T A-frags : [tc=8][lane=64][j=8]   A of 16x16x32: row=f1=tc*16+(l&15), k=g=(l>>4)*8+j
//   [4096,  20480)  Wf2   B-frags : [tn=8][ks=4][lane][8]  B: col=f=tn*16+(l&15), k=ks*32+(l>>4)*8+j
//   [20480, 36864)  W_in2f B-frags: same shape
//   [36864, 53248)  W_out  B-frags: same shape
#define FRAG_WF1 0
#define FRAG_WF2 4096
#define FRAG_WIN 20480
#define FRAG_WOUT 36864

__global__ __launch_bounds__(256) void k_prep(
    const float* __restrict__ Wf1, const float* __restrict__ Wf2,
    const float* __restrict__ Win, const float* __restrict__ Wout,
    unsigned short* __restrict__ frag)
{
    int idx = blockIdx.x * 256 + threadIdx.x;
    if (idx < 4096) {
        int j = idx & 7, lane = (idx >> 3) & 63, tc = idx >> 9;
        int f1 = tc * 16 + (lane & 15);
        int g  = (lane >> 4) * 8 + j;
        frag[idx] = (g < NG) ? f2bf(Wf1[g * NF + f1]) : (unsigned short)0;
    } else if (idx < 20480) {
        int t = idx - 4096;
        int j = t & 7, lane = (t >> 3) & 63, ks = (t >> 9) & 3, tn = t >> 11;
        int f = tn * 16 + (lane & 15);
        int k = ks * 32 + (lane >> 4) * 8 + j;
        frag[idx] = f2bf(Wf2[k * NF + f]);
    } else if (idx < 36864) {
        int t = idx - 20480;
        int j = t & 7, lane = (t >> 3) & 63, ks = (t >> 9) & 3, tn = t >> 11;
        int f = tn * 16 + (lane & 15);
        int k = ks * 32 + (lane >> 4) * 8 + j;
        frag[idx] = f2bf(Win[k * NF + f]);
    } else if (idx < 53248) {
        int t = idx - 36864;
        int j = t & 7, lane = (t >> 3) & 63, ks = (t >> 9) & 3, tn = t >> 11;
        int f = tn * 16 + (lane & 15);
        int k = ks * 32 + (lane >> 4) * 8 + j;
        frag[idx] = f2bf(Wout[k * NF + f]);
    }
}

// y = x @ W_in2f  -> bf16, rows = NB*NA = 8192, BM=32 per block (256 blocks)
__global__ __launch_bounds__(256) void k_in2f(
    const float* __restrict__ x, const unsigned short* __restrict__ frag,
    unsigned short* __restrict__ ybf)
{
    const unsigned short* winfrag = frag + FRAG_WIN;
    const int lane = threadIdx.x & 63, w = threadIdx.x >> 6;
    const int rowbase = blockIdx.x * 32;
    f32x4 acc[2][2];
    f32x4 z = {0.f, 0.f, 0.f, 0.f};
    acc[0][0] = z; acc[0][1] = z; acc[1][0] = z; acc[1][1] = z;
#pragma unroll
    for (int ks = 0; ks < 4; ++ks) {
        bf16x8 a[2];
#pragma unroll
        for (int tm = 0; tm < 2; ++tm) {
            int row = rowbase + tm * 16 + (lane & 15);
            int k0  = ks * 32 + (lane >> 4) * 8;
            const float* p = x + (size_t)row * NF + k0;
            float4 v0 = *(const float4*)p;
            float4 v1 = *(const float4*)(p + 4);
            bf16x8 t;
            t[0] = (short)f2bf(v0.x); t[1] = (short)f2bf(v0.y);
            t[2] = (short)f2bf(v0.z); t[3] = (short)f2bf(v0.w);
            t[4] = (short)f2bf(v1.x); t[5] = (short)f2bf(v1.y);
            t[6] = (short)f2bf(v1.z); t[7] = (short)f2bf(v1.w);
            a[tm] = t;
        }
#pragma unroll
        for (int tn = 0; tn < 2; ++tn) {
            bf16x8 bfr = *(const bf16x8*)(winfrag + ((((w * 2 + tn) * 4 + ks) * 64) + lane) * 8);
#pragma unroll
            for (int tm = 0; tm < 2; ++tm)
                acc[tm][tn] = __builtin_amdgcn_mfma_f32_16x16x32_bf16(a[tm], bfr, acc[tm][tn], 0, 0, 0);
        }
    }
#pragma unroll
    for (int tm = 0; tm < 2; ++tm)
#pragma unroll
        for (int tn = 0; tn < 2; ++tn)
#pragma unroll
            for (int r = 0; r < 4; ++r) {
                int row = rowbase + tm * 16 + (lane >> 4) * 4 + r;
                int f   = w * 32 + tn * 16 + (lane & 15);
                ybf[(size_t)row * NF + f] = f2bf(acc[tm][tn][r]);
            }
}

// Fused per-atom kernel: W1 = ssp(fij@Wf1+b1); W = W1@Wf2+b2; agg = sum_n W*mask*y[nbh]
// Single barrier; y read direct from L2 (per-batch slice = 128KB, shared by 512 blocks).
// LDS = 16.9KB; VGPR ~52 natural -> 8 waves/SIMD feasible WITHOUT forcing (R5 lesson:
// launch_bounds(...,8) forced unified VGPR+AGPR <=64 -> 119MB scratch spill traffic).
__global__ __launch_bounds__(256, 4) void k_cfconv(
    const float* __restrict__ fij, const int* __restrict__ nbh,
    const float* __restrict__ mask, const float* __restrict__ b1,
    const float* __restrict__ b2, const unsigned short* __restrict__ frag,
    const unsigned short* __restrict__ ybf, float* __restrict__ agg)
{
    __shared__ unsigned short sW1T[64 * 128];  // [n][k] bf16, XOR-swizzled byte^((n&7)<<4)
    __shared__ alignas(16) float smask[64];
    __shared__ alignas(16) int   snbh[64];

    const int tid = threadIdx.x, lane = tid & 63, w = tid >> 6;
    const int g = lane >> 4, lc = lane & 15;
    const int atom = blockIdx.x;
    const int bidx = atom >> 9;

    if (tid < 64) {
        smask[tid] = mask[(size_t)atom * NN + tid];
        snbh[tid]  = nbh[(size_t)atom * NN + tid];
    }

    // ---- step A: W1^T = Wf1^T(128x32) @ fij^T(32x64) + b1; wave owns f1-tiles {2w,2w+1} ----
    // fij B-frags straight from global: col n = tn*16+lc, k = g*8+j.
    // Tail group g==3: only k=24 (j=0) is valid -> scalar load + zero fill (no OOB reads).
    const unsigned short* wf1frag = frag + FRAG_WF1;
    const float* fp = fij + (size_t)atom * (NN * NG);
    bf16x8 afr[2], bfr[4];
#pragma unroll
    for (int i = 0; i < 2; ++i)
        afr[i] = *(const bf16x8*)(wf1frag + (((2 * w + i) * 64) + lane) * 8);
    {
        const int g0 = g * 8;
        const bool tail = (g == 3);
#pragma unroll
        for (int tn = 0; tn < 4; ++tn) {
            int n = tn * 16 + lc;
            const float* p = fp + n * NG + g0;
            bf16x8 t;
            if (tail) {
                float v = p[0];                        // k=24, always in-bounds
                t[0] = (short)f2bf(v);
                t[1] = 0; t[2] = 0; t[3] = 0; t[4] = 0; t[5] = 0; t[6] = 0; t[7] = 0;
            } else {
                f32x4u v0 = *(const f32x4u*)p;         // k=g0..g0+7 <= 23, in-bounds
                f32x4u v1 = *(const f32x4u*)(p + 4);
                t[0] = (short)f2bf(v0[0]); t[1] = (short)f2bf(v0[1]);
                t[2] = (short)f2bf(v0[2]); t[3] = (short)f2bf(v0[3]);
                t[4] = (short)f2bf(v1[0]); t[5] = (short)f2bf(v1[1]);
                t[6] = (short)f2bf(v1[2]); t[7] = (short)f2bf(v1[3]);
            }
            bfr[tn] = t;
        }
    }
    f32x4 dW[2][4];
#pragma unroll
    for (int i = 0; i < 2; ++i) {
        int c0 = (2 * w + i) * 16 + g * 4;
        f32x4 ci = *(const f32x4*)(b1 + c0);            // bias folded into MFMA C-in
#pragma unroll
        for (int tn = 0; tn < 4; ++tn)
            dW[i][tn] = __builtin_amdgcn_mfma_f32_16x16x32_bf16(afr[i], bfr[tn], ci, 0, 0, 0);
    }

    // ssp + pack -> swizzled LDS (D-frag: col n = lane&15, rows c = c0+reg, 4 contiguous)
#pragma unroll
    for (int i = 0; i < 2; ++i) {
        int c0 = (2 * w + i) * 16 + g * 4;
#pragma unroll
        for (int tn = 0; tn < 4; ++tn) {
            int n = tn * 16 + lc;
            ushort4 pk;
#pragma unroll
            for (int r = 0; r < 4; ++r)
                ((unsigned short*)&pk)[r] = f2bf(sspf(dW[i][tn][r]));
            *(ushort4*)((char*)sW1T + n * 256 + ((c0 * 2) ^ ((n & 7) << 4))) = pk;
        }
    }
    __syncthreads();

    // ---- step B: W = W1(64x128) @ Wf2(128x128) + b2; wave f-slice [w*32, w*32+32) ----
    const unsigned short* wf2frag = frag + FRAG_WF2;
    const int fbase = w * 32;
    const int fc0 = fbase + lc;
    const float bias0 = b2[fc0], bias1 = b2[fc0 + 16];
    f32x4 acc[4][2];
#pragma unroll
    for (int tm = 0; tm < 4; ++tm) {
        acc[tm][0] = f32x4{bias0, bias0, bias0, bias0};  // b2 folded into C-in
        acc[tm][1] = f32x4{bias1, bias1, bias1, bias1};
    }
#pragma unroll
    for (int ks = 0; ks < 4; ++ks) {
        bf16x8 a4[4];
#pragma unroll
        for (int tm = 0; tm < 4; ++tm) {
            int n  = tm * 16 + lc;
            int kb = ks * 64 + g * 16;             // byte offset of k0*2
            a4[tm] = *(const bf16x8*)((char*)sW1T + n * 256 + (kb ^ ((n & 7) << 4)));
        }
#pragma unroll
        for (int tnl = 0; tnl < 2; ++tnl) {
            int tn = w * 2 + tnl;
            bf16x8 bf2 = *(const bf16x8*)(wf2frag + (((tn * 4 + ks) * 64) + lane) * 8);
#pragma unroll
            for (int tm = 0; tm < 4; ++tm)
                acc[tm][tnl] = __builtin_amdgcn_mfma_f32_16x16x32_bf16(a4[tm], bf2, acc[tm][tnl], 0, 0, 0);
        }
    }

    // ---- step C: agg[f] = sum_n W[n][f] * mask[n] * y[b, nbh[n], f] ----
    // y read direct from global (L2-hot 128KB batch slice); 2 u16 loads share one vaddr
    // (offset 0 / +32B immediate). n per thread: g*4 + tm*16 + r (16 rows).
    float aggv0 = 0.f, aggv1 = 0.f;
    const unsigned short* yb = ybf + (size_t)bidx * NA * NF;
#pragma unroll
    for (int tm = 0; tm < 4; ++tm) {
        f32x4 m4 = *(const f32x4*)(smask + tm * 16 + g * 4);
        int4  nb4 = *(const int4*)(snbh + tm * 16 + g * 4);
#pragma unroll
        for (int r = 0; r < 4; ++r) {
            int yrow = (r == 0) ? nb4.x : (r == 1) ? nb4.y : (r == 2) ? nb4.z : nb4.w;
            const unsigned short* yp = yb + (size_t)yrow * NF + fc0;
            float y0 = bf2f(yp[0]);
            float y1 = bf2f(yp[16]);
            aggv0 = fmaf(acc[tm][0][r] * m4[r], y0, aggv0);
            aggv1 = fmaf(acc[tm][1][r] * m4[r], y1, aggv1);
        }
    }
    aggv0 += __shfl_xor(aggv0, 16); aggv1 += __shfl_xor(aggv1, 16);
    aggv0 += __shfl_xor(aggv0, 32); aggv1 += __shfl_xor(aggv1, 32);
    if (lane < 16) {
        float* ap = agg + (size_t)atom * NF + fbase;
        ap[lane] = aggv0;
        ap[16 + lane] = aggv1;
    }
}

// out = ssp(agg @ W_out + b_out), rows = 8192, BM=32 (256 blocks)
__global__ __launch_bounds__(256) void k_out(
    const float* __restrict__ agg, const unsigned short* __restrict__ frag,
    const float* __restrict__ bout, float* __restrict__ out)
{
    const unsigned short* wofrag = frag + FRAG_WOUT;
    const int lane = threadIdx.x & 63, w = threadIdx.x >> 6;
    const int rowbase = blockIdx.x * 32;
    const int f0 = w * 32 + (lane & 15);
    const float bo0 = bout[f0], bo1 = bout[f0 + 16];
    f32x4 acc[2][2];
    acc[0][0] = f32x4{bo0, bo0, bo0, bo0};
    acc[1][0] = f32x4{bo0, bo0, bo0, bo0};
    acc[0][1] = f32x4{bo1, bo1, bo1, bo1};
    acc[1][1] = f32x4{bo1, bo1, bo1, bo1};
#pragma unroll
    for (int ks = 0; ks < 4; ++ks) {
        bf16x8 a[2];
#pragma unroll
        for (int tm = 0; tm < 2; ++tm) {
            int row = rowbase + tm * 16 + (lane & 15);
            int k0  = ks * 32 + (lane >> 4) * 8;
            const float* p = agg + (size_t)row * NF + k0;
            float4 v0 = *(const float4*)p;
            float4 v1 = *(const float4*)(p + 4);
            bf16x8 t;
            t[0] = (short)f2bf(v0.x); t[1] = (short)f2bf(v0.y);
            t[2] = (short)f2bf(v0.z); t[3] = (short)f2bf(v0.w);
            t[4] = (short)f2bf(v1.x); t[5] = (short)f2bf(v1.y);
            t[6] = (short)f2bf(v1.z); t[7] = (short)f2bf(v1.w);
            a[tm] = t;
        }
#pragma unroll
        for (int tn = 0; tn < 2; ++tn) {
            bf16x8 bfr = *(const bf16x8*)(wofrag + ((((w * 2 + tn) * 4 + ks) * 64) + lane) * 8);
#pragma unroll
            for (int tm = 0; tm < 2; ++tm)
                acc[tm][tn] = __builtin_amdgcn_mfma_f32_16x16x32_bf16(a[tm], bfr, acc[tm][tn], 0, 0, 0);
        }
    }
#pragma unroll
    for (int tm = 0; tm < 2; ++tm)
#pragma unroll
        for (int tn = 0; tn < 2; ++tn)
#pragma unroll
            for (int r = 0; r < 4; ++r) {
                int row = rowbase + tm * 16 + (lane >> 4) * 4 + r;
                int f   = w * 32 + tn * 16 + (lane & 15);
                out[(size_t)row * NF + f] = sspf(acc[tm][tn][r]);
            }
}

extern "C" void kernel_launch(void* const* d_in, const int* in_sizes, int n_in,
                              void* d_out, int out_size, void* d_ws, size_t ws_size,
                              hipStream_t stream)
{
    (void)in_sizes; (void)n_in; (void)out_size; (void)ws_size;
    const float* x    = (const float*)d_in[0];
    // d_in[1] = r_ij (unused by reference)
    const float* fij  = (const float*)d_in[2];
    const int*   nbh  = (const int*)d_in[3];
    const float* mask = (const float*)d_in[4];
    const float* Win  = (const float*)d_in[5];
    const float* Wf1  = (const float*)d_in[6];
    const float* b1   = (const float*)d_in[7];
    const float* Wf2  = (const float*)d_in[8];
    const float* b2   = (const float*)d_in[9];
    const float* Wout = (const float*)d_in[10];
    const float* bout = (const float*)d_in[11];
    float* out = (float*)d_out;

    // ws layout: [0,106496) frags (53248 ushorts) | [106496, +2MB) y bf16 | [2203648, +4MB) agg f32
    unsigned short* frag = (unsigned short*)d_ws;
    unsigned short* ybf  = (unsigned short*)((char*)d_ws + 106496);
    float*          agg  = (float*)((char*)d_ws + 2203648);

    k_prep  <<<208,  256, 0, stream>>>(Wf1, Wf2, Win, Wout, frag);
    k_in2f  <<<256,  256, 0, stream>>>(x, frag, ybf);
    k_cfconv<<<8192, 256, 0, stream>>>(fij, nbh, mask, b1, b2, frag, ybf, agg);
    k_out   <<<256,  256, 0, stream>>>(agg, frag, bout, out);
}

// Round 8
// 60.189 us; speedup vs baseline: 1.6649x; 1.2621x over previous
//
#include <hip/hip_runtime.h>

typedef __attribute__((ext_vector_type(8))) short bf16x8;
typedef __attribute__((ext_vector_type(4))) float f32x4;
typedef __attribute__((ext_vector_type(4))) unsigned int u32x4;

#define LOG2F 0.69314718055994531f
#define LOG2EF 1.4426950408889634f

// Problem dims (fixed by harness)
#define NB 16
#define NA 512
#define NN 64
#define NG 25
#define NF 128

__device__ __forceinline__ unsigned short f2bf(float x) {
    __bf16 h = (__bf16)x;                       // hw cvt (RNE), pairs to v_cvt_pk_bf16_f32
    return __builtin_bit_cast(unsigned short, h);
}
__device__ __forceinline__ float bf2f(unsigned short h) {
    union { unsigned int u; float f; } c; c.u = ((unsigned int)h) << 16;
    return c.f;
}
// ssp on pre-scaled input s = x*log2(e):  ln(1+e^x)-ln2 = ln2*(log2(1+2^s)-1)
__device__ __forceinline__ float ssp2(float s) {
    float t = __builtin_amdgcn_exp2f(s);                            // v_exp_f32
    return fmaf(__builtin_amdgcn_logf(1.0f + t), LOG2F, -LOG2F);    // add, v_log_f32, fma
}

// ws fragment layout (ushort units):
//   [0,      4096)  Wf1^T A-frags (PRE-SCALED by log2e): [tc=8][lane=64][j=8]
//   [4096,  20480)  Wf2   B-frags : [tn=8][ks=4][lane][8]  B: col=f=tn*16+(l&15), k=ks*32+(l>>4)*8+j
//   [20480, 36864)  W_in2f B-frags: same shape
//   [36864, 53248)  W_out  B-frags: same shape
#define FRAG_WF1 0
#define FRAG_WF2 4096
#define FRAG_WIN 20480
#define FRAG_WOUT 36864

__global__ __launch_bounds__(256) void k_prep(
    const float* __restrict__ Wf1, const float* __restrict__ Wf2,
    const float* __restrict__ Win, const float* __restrict__ Wout,
    unsigned short* __restrict__ frag)
{
    int idx = blockIdx.x * 256 + threadIdx.x;
    if (idx < 4096) {
        int j = idx & 7, lane = (idx >> 3) & 63, tc = idx >> 9;
        int f1 = tc * 16 + (lane & 15);
        int g  = (lane >> 4) * 8 + j;
        frag[idx] = (g < NG) ? f2bf(Wf1[g * NF + f1] * LOG2EF) : (unsigned short)0;
    } else if (idx < 20480) {
        int t = idx - 4096;
        int j = t & 7, lane = (t >> 3) & 63, ks = (t >> 9) & 3, tn = t >> 11;
        int f = tn * 16 + (lane & 15);
        int k = ks * 32 + (lane >> 4) * 8 + j;
        frag[idx] = f2bf(Wf2[k * NF + f]);
    } else if (idx < 36864) {
        int t = idx - 20480;
        int j = t & 7, lane = (t >> 3) & 63, ks = (t >> 9) & 3, tn = t >> 11;
        int f = tn * 16 + (lane & 15);
        int k = ks * 32 + (lane >> 4) * 8 + j;
        frag[idx] = f2bf(Win[k * NF + f]);
    } else if (idx < 53248) {
        int t = idx - 36864;
        int j = t & 7, lane = (t >> 3) & 63, ks = (t >> 9) & 3, tn = t >> 11;
        int f = tn * 16 + (lane & 15);
        int k = ks * 32 + (lane >> 4) * 8 + j;
        frag[idx] = f2bf(Wout[k * NF + f]);
    }
}

// y = x @ W_in2f  -> bf16, rows = NB*NA = 8192, BM=32 per block (256 blocks)
__global__ __launch_bounds__(256) void k_in2f(
    const float* __restrict__ x, const unsigned short* __restrict__ frag,
    unsigned short* __restrict__ ybf)
{
    const unsigned short* winfrag = frag + FRAG_WIN;
    const int lane = threadIdx.x & 63, w = threadIdx.x >> 6;
    const int rowbase = blockIdx.x * 32;
    f32x4 acc[2][2];
    f32x4 z = {0.f, 0.f, 0.f, 0.f};
    acc[0][0] = z; acc[0][1] = z; acc[1][0] = z; acc[1][1] = z;
#pragma unroll
    for (int ks = 0; ks < 4; ++ks) {
        bf16x8 a[2];
#pragma unroll
        for (int tm = 0; tm < 2; ++tm) {
            int row = rowbase + tm * 16 + (lane & 15);
            int k0  = ks * 32 + (lane >> 4) * 8;
            const float* p = x + (size_t)row * NF + k0;
            float4 v0 = *(const float4*)p;
            float4 v1 = *(const float4*)(p + 4);
            bf16x8 t;
            t[0] = (short)f2bf(v0.x); t[1] = (short)f2bf(v0.y);
            t[2] = (short)f2bf(v0.z); t[3] = (short)f2bf(v0.w);
            t[4] = (short)f2bf(v1.x); t[5] = (short)f2bf(v1.y);
            t[6] = (short)f2bf(v1.z); t[7] = (short)f2bf(v1.w);
            a[tm] = t;
        }
#pragma unroll
        for (int tn = 0; tn < 2; ++tn) {
            bf16x8 bfr = *(const bf16x8*)(winfrag + ((((w * 2 + tn) * 4 + ks) * 64) + lane) * 8);
#pragma unroll
            for (int tm = 0; tm < 2; ++tm)
                acc[tm][tn] = __builtin_amdgcn_mfma_f32_16x16x32_bf16(a[tm], bfr, acc[tm][tn], 0, 0, 0);
        }
    }
#pragma unroll
    for (int tm = 0; tm < 2; ++tm)
#pragma unroll
        for (int tn = 0; tn < 2; ++tn)
#pragma unroll
            for (int r = 0; r < 4; ++r) {
                int row = rowbase + tm * 16 + (lane >> 4) * 4 + r;
                int f   = w * 32 + tn * 16 + (lane & 15);
                ybf[(size_t)row * NF + f] = f2bf(acc[tm][tn][r]);
            }
}

// Fused per-atom kernel: W1 = ssp(fij@Wf1+b1); W = W1@Wf2+b2; agg = sum_n W*mask*y[nbh]
// fij staged raw (f32) to LDS via global_load_lds (zero VALU), frag-built from LDS.
// ssp in exp2 form (weights pre-scaled by log2e). y read direct from L2.
__global__ __launch_bounds__(256, 4) void k_cfconv(
    const float* __restrict__ fij, const int* __restrict__ nbh,
    const float* __restrict__ mask, const float* __restrict__ b1,
    const float* __restrict__ b2, const unsigned short* __restrict__ frag,
    const unsigned short* __restrict__ ybf, float* __restrict__ agg)
{
    __shared__ float sfij[1608];               // raw [n][25] f32 + 8 pad dwords (reads to 1606)
    __shared__ unsigned short sW1T[64 * 128];  // [n][k] bf16, XOR-swizzled byte^((n&7)<<4)
    __shared__ alignas(16) float smask[64];
    __shared__ alignas(16) int   snbh[64];

    const int tid = threadIdx.x, lane = tid & 63, w = tid >> 6;
    const int g = lane >> 4, lc = lane & 15;
    const int atom = blockIdx.x;
    const int bidx = atom >> 9;

    if (tid < 64) {
        smask[tid] = mask[(size_t)atom * NN + tid];
        snbh[tid]  = nbh[(size_t)atom * NN + tid];
    }

    // ---- stage raw fij (6400B) -> LDS, 7 global_load_lds split across waves ----
    {
        const char* fb = (const char*)(fij + (size_t)atom * (NN * NG));
        // chunks 0..3 (1KB each): wave w
        __builtin_amdgcn_global_load_lds(
            (const __attribute__((address_space(1))) void*)(fb + w * 1024 + lane * 16),
            (__attribute__((address_space(3))) void*)((char*)sfij + w * 1024), 16, 0, 0);
        if (w < 2) {  // chunks 4,5
            __builtin_amdgcn_global_load_lds(
                (const __attribute__((address_space(1))) void*)(fb + (w + 4) * 1024 + lane * 16),
                (__attribute__((address_space(3))) void*)((char*)sfij + (w + 4) * 1024), 16, 0, 0);
        }
        if (w == 3) { // tail bytes 6144..6399 (64 lanes x 4B)
            __builtin_amdgcn_global_load_lds(
                (const __attribute__((address_space(1))) void*)(fb + 6144 + lane * 4),
                (__attribute__((address_space(3))) void*)((char*)sfij + 6144), 4, 0, 0);
        }
    }

    // ---- A-frags (Wf1^T, pre-scaled by log2e) from global while staging lands ----
    const unsigned short* wf1frag = frag + FRAG_WF1;
    bf16x8 afr[2], bfr[4];
#pragma unroll
    for (int i = 0; i < 2; ++i)
        afr[i] = *(const bf16x8*)(wf1frag + (((2 * w + i) * 64) + lane) * 8);

    __syncthreads();   // sfij + smask/snbh visible (vmcnt drained before s_barrier)

    // ---- build fij B-frags from LDS: col n = tn*16+lc, k = g*8+j; zero k>=25 ----
    {
        const int g0 = g * 8;
        const unsigned int m0 = (g == 3) ? 0x0000FFFFu : 0xFFFFFFFFu;  // j0 keep, j1 zero if tail
        const unsigned int m1 = (g == 3) ? 0u : 0xFFFFFFFFu;           // j2..7 zero if tail
#pragma unroll
        for (int tn = 0; tn < 4; ++tn) {
            int n = tn * 16 + lc;
            const float* p = sfij + n * NG + g0;   // consecutive 8 dwords (2-way banks, free)
            bf16x8 t;
            t[0] = (short)f2bf(p[0]); t[1] = (short)f2bf(p[1]);
            t[2] = (short)f2bf(p[2]); t[3] = (short)f2bf(p[3]);
            t[4] = (short)f2bf(p[4]); t[5] = (short)f2bf(p[5]);
            t[6] = (short)f2bf(p[6]); t[7] = (short)f2bf(p[7]);
            u32x4 tv = __builtin_bit_cast(u32x4, t);
            tv[0] &= m0; tv[1] &= m1; tv[2] &= m1; tv[3] &= m1;
            bfr[tn] = __builtin_bit_cast(bf16x8, tv);
        }
    }

    // ---- step A: W1^T·log2e = (Wf1^T·log2e)(128x32) @ fij^T(32x64) + b1·log2e ----
    f32x4 dW[2][4];
#pragma unroll
    for (int i = 0; i < 2; ++i) {
        int c0 = (2 * w + i) * 16 + g * 4;
        f32x4 ci = *(const f32x4*)(b1 + c0) * LOG2EF;   // bias (scaled) as MFMA C-in
#pragma unroll
        for (int tn = 0; tn < 4; ++tn)
            dW[i][tn] = __builtin_amdgcn_mfma_f32_16x16x32_bf16(afr[i], bfr[tn], ci, 0, 0, 0);
    }

    // ssp (exp2 form) + pack -> swizzled LDS
#pragma unroll
    for (int i = 0; i < 2; ++i) {
        int c0 = (2 * w + i) * 16 + g * 4;
#pragma unroll
        for (int tn = 0; tn < 4; ++tn) {
            int n = tn * 16 + lc;
            ushort4 pk;
#pragma unroll
            for (int r = 0; r < 4; ++r)
                ((unsigned short*)&pk)[r] = f2bf(ssp2(dW[i][tn][r]));
            *(ushort4*)((char*)sW1T + n * 256 + ((c0 * 2) ^ ((n & 7) << 4))) = pk;
        }
    }
    __syncthreads();

    // ---- step B: W = W1(64x128) @ Wf2(128x128) + b2; wave f-slice [w*32, w*32+32) ----
    const unsigned short* wf2frag = frag + FRAG_WF2;
    const int fbase = w * 32;
    const int fc0 = fbase + lc;
    const float bias0 = b2[fc0], bias1 = b2[fc0 + 16];
    f32x4 acc[4][2];
#pragma unroll
    for (int tm = 0; tm < 4; ++tm) {
        acc[tm][0] = f32x4{bias0, bias0, bias0, bias0};  // b2 folded into C-in
        acc[tm][1] = f32x4{bias1, bias1, bias1, bias1};
    }
#pragma unroll
    for (int ks = 0; ks < 4; ++ks) {
        bf16x8 a4[4];
#pragma unroll
        for (int tm = 0; tm < 4; ++tm) {
            int n  = tm * 16 + lc;
            int kb = ks * 64 + g * 16;             // byte offset of k0*2
            a4[tm] = *(const bf16x8*)((char*)sW1T + n * 256 + (kb ^ ((n & 7) << 4)));
        }
#pragma unroll
        for (int tnl = 0; tnl < 2; ++tnl) {
            int tn = w * 2 + tnl;
            bf16x8 bf2 = *(const bf16x8*)(wf2frag + (((tn * 4 + ks) * 64) + lane) * 8);
#pragma unroll
            for (int tm = 0; tm < 4; ++tm)
                acc[tm][tnl] = __builtin_amdgcn_mfma_f32_16x16x32_bf16(a4[tm], bf2, acc[tm][tnl], 0, 0, 0);
        }
    }

    // ---- step C: agg[f] = sum_n W[n][f] * mask[n] * y[b, nbh[n], f] ----
    float aggv0 = 0.f, aggv1 = 0.f;
    const unsigned short* yb = ybf + (size_t)bidx * NA * NF;
#pragma unroll
    for (int tm = 0; tm < 4; ++tm) {
        f32x4 m4 = *(const f32x4*)(smask + tm * 16 + g * 4);
        int4  nb4 = *(const int4*)(snbh + tm * 16 + g * 4);
#pragma unroll
        for (int r = 0; r < 4; ++r) {
            int yrow = (r == 0) ? nb4.x : (r == 1) ? nb4.y : (r == 2) ? nb4.z : nb4.w;
            const unsigned short* yp = yb + (size_t)yrow * NF + fc0;
            float y0 = bf2f(yp[0]);
            float y1 = bf2f(yp[16]);
            aggv0 = fmaf(acc[tm][0][r] * m4[r], y0, aggv0);
            aggv1 = fmaf(acc[tm][1][r] * m4[r], y1, aggv1);
        }
    }
    aggv0 += __shfl_xor(aggv0, 16); aggv1 += __shfl_xor(aggv1, 16);
    aggv0 += __shfl_xor(aggv0, 32); aggv1 += __shfl_xor(aggv1, 32);
    if (lane < 16) {
        float* ap = agg + (size_t)atom * NF + fbase;
        ap[lane] = aggv0;
        ap[16 + lane] = aggv1;
    }
}

// out = ssp(agg @ W_out + b_out), rows = 8192, BM=32 (256 blocks)
__global__ __launch_bounds__(256) void k_out(
    const float* __restrict__ agg, const unsigned short* __restrict__ frag,
    const float* __restrict__ bout, float* __restrict__ out)
{
    const unsigned short* wofrag = frag + FRAG_WOUT;
    const int lane = threadIdx.x & 63, w = threadIdx.x >> 6;
    const int rowbase = blockIdx.x * 32;
    const int f0 = w * 32 + (lane & 15);
    const float bo0 = bout[f0], bo1 = bout[f0 + 16];
    f32x4 acc[2][2];
    acc[0][0] = f32x4{bo0, bo0, bo0, bo0};
    acc[1][0] = f32x4{bo0, bo0, bo0, bo0};
    acc[0][1] = f32x4{bo1, bo1, bo1, bo1};
    acc[1][1] = f32x4{bo1, bo1, bo1, bo1};
#pragma unroll
    for (int ks = 0; ks < 4; ++ks) {
        bf16x8 a[2];
#pragma unroll
        for (int tm = 0; tm < 2; ++tm) {
            int row = rowbase + tm * 16 + (lane & 15);
            int k0  = ks * 32 + (lane >> 4) * 8;
            const float* p = agg + (size_t)row * NF + k0;
            float4 v0 = *(const float4*)p;
            float4 v1 = *(const float4*)(p + 4);
            bf16x8 t;
            t[0] = (short)f2bf(v0.x); t[1] = (short)f2bf(v0.y);
            t[2] = (short)f2bf(v0.z); t[3] = (short)f2bf(v0.w);
            t[4] = (short)f2bf(v1.x); t[5] = (short)f2bf(v1.y);
            t[6] = (short)f2bf(v1.z); t[7] = (short)f2bf(v1.w);
            a[tm] = t;
        }
#pragma unroll
        for (int tn = 0; tn < 2; ++tn) {
            bf16x8 bfr = *(const bf16x8*)(wofrag + ((((w * 2 + tn) * 4 + ks) * 64) + lane) * 8);
#pragma unroll
            for (int tm = 0; tm < 2; ++tm)
                acc[tm][tn] = __builtin_amdgcn_mfma_f32_16x16x32_bf16(a[tm], bfr, acc[tm][tn], 0, 0, 0);
        }
    }
    float lg2 = LOG2EF;
#pragma unroll
    for (int tm = 0; tm < 2; ++tm)
#pragma unroll
        for (int tn = 0; tn < 2; ++tn)
#pragma unroll
            for (int r = 0; r < 4; ++r) {
                int row = rowbase + tm * 16 + (lane >> 4) * 4 + r;
                int f   = w * 32 + tn * 16 + (lane & 15);
                out[(size_t)row * NF + f] = ssp2(acc[tm][tn][r] * lg2);
            }
}

extern "C" void kernel_launch(void* const* d_in, const int* in_sizes, int n_in,
                              void* d_out, int out_size, void* d_ws, size_t ws_size,
                              hipStream_t stream)
{
    (void)in_sizes; (void)n_in; (void)out_size; (void)ws_size;
    const float* x    = (const float*)d_in[0];
    // d_in[1] = r_ij (unused by reference)
    const float* fij  = (const float*)d_in[2];
    const int*   nbh  = (const int*)d_in[3];
    const float* mask = (const float*)d_in[4];
    const float* Win  = (const float*)d_in[5];
    const float* Wf1  = (const float*)d_in[6];
    const float* b1   = (const float*)d_in[7];
    const float* Wf2  = (const float*)d_in[8];
    const float* b2   = (const float*)d_in[9];
    const float* Wout = (const float*)d_in[10];
    const float* bout = (const float*)d_in[11];
    float* out = (float*)d_out;

    // ws layout: [0,106496) frags (53248 ushorts) | [106496, +2MB) y bf16 | [2203648, +4MB) agg f32
    unsigned short* frag = (unsigned short*)d_ws;
    unsigned short* ybf  = (unsigned short*)((char*)d_ws + 106496);
    float*          agg  = (float*)((char*)d_ws + 2203648);

    k_prep  <<<208,  256, 0, stream>>>(Wf1, Wf2, Win, Wout, frag);
    k_in2f  <<<256,  256, 0, stream>>>(x, frag, ybf);
    k_cfconv<<<8192, 256, 0, stream>>>(fij, nbh, mask, b1, b2, frag, ybf, agg);
    k_out   <<<256,  256, 0, stream>>>(agg, frag, bout, out);
}

// Round 9
// 59.297 us; speedup vs baseline: 1.6900x; 1.0150x over previous
//
#include <hip/hip_runtime.h>

typedef __attribute__((ext_vector_type(8))) short bf16x8;
typedef __attribute__((ext_vector_type(4))) float f32x4;
typedef __attribute__((ext_vector_type(4))) unsigned int u32x4;

#define LOG2F 0.69314718055994531f
#define LOG2EF 1.4426950408889634f

// Problem dims (fixed by harness)
#define NB 16
#define NA 512
#define NN 64
#define NG 25
#define NF 128

__device__ __forceinline__ unsigned short f2bf(float x) {
    __bf16 h = (__bf16)x;                       // hw cvt (RNE), pairs to v_cvt_pk_bf16_f32
    return __builtin_bit_cast(unsigned short, h);
}
__device__ __forceinline__ float bf2f(unsigned short h) {
    union { unsigned int u; float f; } c; c.u = ((unsigned int)h) << 16;
    return c.f;
}
// ssp on pre-scaled input s = x*log2(e):  ln(1+e^x)-ln2 = ln2*(log2(1+2^s)-1)
__device__ __forceinline__ float ssp2(float s) {
    float t = __builtin_amdgcn_exp2f(s);                            // v_exp_f32
    return fmaf(__builtin_amdgcn_logf(1.0f + t), LOG2F, -LOG2F);    // add, v_log_f32, fma
}

// ws fragment layout (ushort units):
//   [0,      4096)  Wf1^T A-frags (PRE-SCALED by log2e): [tc=8][lane=64][j=8]
//   [4096,  20480)  Wf2   B-frags : [tn=8][ks=4][lane][8]  B: col=f=tn*16+(l&15), k=ks*32+(l>>4)*8+j
//   [20480, 36864)  W_in2f B-frags: same shape
//   [36864, 53248)  W_out  B-frags: same shape
#define FRAG_WF1 0
#define FRAG_WF2 4096
#define FRAG_WIN 20480
#define FRAG_WOUT 36864

__global__ __launch_bounds__(256) void k_prep(
    const float* __restrict__ Wf1, const float* __restrict__ Wf2,
    const float* __restrict__ Win, const float* __restrict__ Wout,
    unsigned short* __restrict__ frag)
{
    int idx = blockIdx.x * 256 + threadIdx.x;
    if (idx < 4096) {
        int j = idx & 7, lane = (idx >> 3) & 63, tc = idx >> 9;
        int f1 = tc * 16 + (lane & 15);
        int g  = (lane >> 4) * 8 + j;
        frag[idx] = (g < NG) ? f2bf(Wf1[g * NF + f1] * LOG2EF) : (unsigned short)0;
    } else if (idx < 20480) {
        int t = idx - 4096;
        int j = t & 7, lane = (t >> 3) & 63, ks = (t >> 9) & 3, tn = t >> 11;
        int f = tn * 16 + (lane & 15);
        int k = ks * 32 + (lane >> 4) * 8 + j;
        frag[idx] = f2bf(Wf2[k * NF + f]);
    } else if (idx < 36864) {
        int t = idx - 20480;
        int j = t & 7, lane = (t >> 3) & 63, ks = (t >> 9) & 3, tn = t >> 11;
        int f = tn * 16 + (lane & 15);
        int k = ks * 32 + (lane >> 4) * 8 + j;
        frag[idx] = f2bf(Win[k * NF + f]);
    } else if (idx < 53248) {
        int t = idx - 36864;
        int j = t & 7, lane = (t >> 3) & 63, ks = (t >> 9) & 3, tn = t >> 11;
        int f = tn * 16 + (lane & 15);
        int k = ks * 32 + (lane >> 4) * 8 + j;
        frag[idx] = f2bf(Wout[k * NF + f]);
    }
}

// y = x @ W_in2f  -> bf16, rows = NB*NA = 8192, BM=32 per block (256 blocks)
__global__ __launch_bounds__(256) void k_in2f(
    const float* __restrict__ x, const unsigned short* __restrict__ frag,
    unsigned short* __restrict__ ybf)
{
    const unsigned short* winfrag = frag + FRAG_WIN;
    const int lane = threadIdx.x & 63, w = threadIdx.x >> 6;
    const int rowbase = blockIdx.x * 32;
    f32x4 acc[2][2];
    f32x4 z = {0.f, 0.f, 0.f, 0.f};
    acc[0][0] = z; acc[0][1] = z; acc[1][0] = z; acc[1][1] = z;
#pragma unroll
    for (int ks = 0; ks < 4; ++ks) {
        bf16x8 a[2];
#pragma unroll
        for (int tm = 0; tm < 2; ++tm) {
            int row = rowbase + tm * 16 + (lane & 15);
            int k0  = ks * 32 + (lane >> 4) * 8;
            const float* p = x + (size_t)row * NF + k0;
            float4 v0 = *(const float4*)p;
            float4 v1 = *(const float4*)(p + 4);
            bf16x8 t;
            t[0] = (short)f2bf(v0.x); t[1] = (short)f2bf(v0.y);
            t[2] = (short)f2bf(v0.z); t[3] = (short)f2bf(v0.w);
            t[4] = (short)f2bf(v1.x); t[5] = (short)f2bf(v1.y);
            t[6] = (short)f2bf(v1.z); t[7] = (short)f2bf(v1.w);
            a[tm] = t;
        }
#pragma unroll
        for (int tn = 0; tn < 2; ++tn) {
            bf16x8 bfr = *(const bf16x8*)(winfrag + ((((w * 2 + tn) * 4 + ks) * 64) + lane) * 8);
#pragma unroll
            for (int tm = 0; tm < 2; ++tm)
                acc[tm][tn] = __builtin_amdgcn_mfma_f32_16x16x32_bf16(a[tm], bfr, acc[tm][tn], 0, 0, 0);
        }
    }
#pragma unroll
    for (int tm = 0; tm < 2; ++tm)
#pragma unroll
        for (int tn = 0; tn < 2; ++tn)
#pragma unroll
            for (int r = 0; r < 4; ++r) {
                int row = rowbase + tm * 16 + (lane >> 4) * 4 + r;
                int f   = w * 32 + tn * 16 + (lane & 15);
                ybf[(size_t)row * NF + f] = f2bf(acc[tm][tn][r]);
            }
}

// Fused per-atom kernel: W1 = ssp(fij@Wf1+b1); W = W1@Wf2+b2; agg = sum_n W*mask*y[nbh]
// sfij (raw f32 staging) and sW1T (bf16 W1^T) OVERLAY the same LDS (disjoint lifetimes,
// separated by a barrier): LDS 16.9KB -> 8 blocks/CU (occupancy lever).
__global__ __launch_bounds__(256, 4) void k_cfconv(
    const float* __restrict__ fij, const int* __restrict__ nbh,
    const float* __restrict__ mask, const float* __restrict__ b1,
    const float* __restrict__ b2, const unsigned short* __restrict__ frag,
    const unsigned short* __restrict__ ybf, float* __restrict__ agg)
{
    __shared__ alignas(16) char smem[16896];
    float* sfij          = (float*)smem;            // [0, 6432)  raw [n][25] f32 (phase 1)
    unsigned short* sW1T = (unsigned short*)smem;   // [0,16384)  [n][k] bf16 swizzled (phase 2)
    float* smask         = (float*)(smem + 16384);  // [16384,16640)
    int*   snbh          = (int*)(smem + 16640);    // [16640,16896)

    const int tid = threadIdx.x, lane = tid & 63, w = tid >> 6;
    const int g = lane >> 4, lc = lane & 15;
    const int atom = blockIdx.x;
    const int bidx = atom >> 9;

    if (tid < 64) {
        smask[tid] = mask[(size_t)atom * NN + tid];
        snbh[tid]  = nbh[(size_t)atom * NN + tid];
    }

    // ---- stage raw fij (6400B) -> LDS, 7 global_load_lds split across waves ----
    {
        const char* fb = (const char*)(fij + (size_t)atom * (NN * NG));
        __builtin_amdgcn_global_load_lds(
            (const __attribute__((address_space(1))) void*)(fb + w * 1024 + lane * 16),
            (__attribute__((address_space(3))) void*)((char*)sfij + w * 1024), 16, 0, 0);
        if (w < 2) {
            __builtin_amdgcn_global_load_lds(
                (const __attribute__((address_space(1))) void*)(fb + (w + 4) * 1024 + lane * 16),
                (__attribute__((address_space(3))) void*)((char*)sfij + (w + 4) * 1024), 16, 0, 0);
        }
        if (w == 3) {
            __builtin_amdgcn_global_load_lds(
                (const __attribute__((address_space(1))) void*)(fb + 6144 + lane * 4),
                (__attribute__((address_space(3))) void*)((char*)sfij + 6144), 4, 0, 0);
        }
    }

    // ---- A-frags (Wf1^T, pre-scaled by log2e) from global while staging lands ----
    const unsigned short* wf1frag = frag + FRAG_WF1;
    bf16x8 afr[2], bfr[4];
#pragma unroll
    for (int i = 0; i < 2; ++i)
        afr[i] = *(const bf16x8*)(wf1frag + (((2 * w + i) * 64) + lane) * 8);

    __syncthreads();   // sfij + smask/snbh visible (vmcnt drained before s_barrier)

    // ---- build fij B-frags from LDS -> registers: col n = tn*16+lc, k = g*8+j ----
    {
        const int g0 = g * 8;
        const unsigned int m0 = (g == 3) ? 0x0000FFFFu : 0xFFFFFFFFu;
        const unsigned int m1 = (g == 3) ? 0u : 0xFFFFFFFFu;
#pragma unroll
        for (int tn = 0; tn < 4; ++tn) {
            int n = tn * 16 + lc;
            const float* p = sfij + n * NG + g0;
            bf16x8 t;
            t[0] = (short)f2bf(p[0]); t[1] = (short)f2bf(p[1]);
            t[2] = (short)f2bf(p[2]); t[3] = (short)f2bf(p[3]);
            t[4] = (short)f2bf(p[4]); t[5] = (short)f2bf(p[5]);
            t[6] = (short)f2bf(p[6]); t[7] = (short)f2bf(p[7]);
            u32x4 tv = __builtin_bit_cast(u32x4, t);
            tv[0] &= m0; tv[1] &= m1; tv[2] &= m1; tv[3] &= m1;
            bfr[tn] = __builtin_bit_cast(bf16x8, tv);
        }
    }

    __syncthreads();   // all sfij reads done -> safe to overwrite smem with sW1T

    // ---- step A: W1^T·log2e = (Wf1^T·log2e)(128x32) @ fij^T(32x64) + b1·log2e ----
    f32x4 dW[2][4];
#pragma unroll
    for (int i = 0; i < 2; ++i) {
        int c0 = (2 * w + i) * 16 + g * 4;
        f32x4 ci = *(const f32x4*)(b1 + c0) * LOG2EF;   // bias (scaled) as MFMA C-in
#pragma unroll
        for (int tn = 0; tn < 4; ++tn)
            dW[i][tn] = __builtin_amdgcn_mfma_f32_16x16x32_bf16(afr[i], bfr[tn], ci, 0, 0, 0);
    }

    // ssp (exp2 form) + pack -> swizzled LDS
#pragma unroll
    for (int i = 0; i < 2; ++i) {
        int c0 = (2 * w + i) * 16 + g * 4;
#pragma unroll
        for (int tn = 0; tn < 4; ++tn) {
            int n = tn * 16 + lc;
            ushort4 pk;
#pragma unroll
            for (int r = 0; r < 4; ++r)
                ((unsigned short*)&pk)[r] = f2bf(ssp2(dW[i][tn][r]));
            *(ushort4*)((char*)sW1T + n * 256 + ((c0 * 2) ^ ((n & 7) << 4))) = pk;
        }
    }
    __syncthreads();

    // ---- step B: W = W1(64x128) @ Wf2(128x128) + b2; wave f-slice [w*32, w*32+32) ----
    const unsigned short* wf2frag = frag + FRAG_WF2;
    const int fbase = w * 32;
    const int fc0 = fbase + lc;
    const float bias0 = b2[fc0], bias1 = b2[fc0 + 16];
    f32x4 acc[4][2];
#pragma unroll
    for (int tm = 0; tm < 4; ++tm) {
        acc[tm][0] = f32x4{bias0, bias0, bias0, bias0};  // b2 folded into C-in
        acc[tm][1] = f32x4{bias1, bias1, bias1, bias1};
    }
#pragma unroll
    for (int ks = 0; ks < 4; ++ks) {
        bf16x8 a4[4];
#pragma unroll
        for (int tm = 0; tm < 4; ++tm) {
            int n  = tm * 16 + lc;
            int kb = ks * 64 + g * 16;             // byte offset of k0*2
            a4[tm] = *(const bf16x8*)((char*)sW1T + n * 256 + (kb ^ ((n & 7) << 4)));
        }
#pragma unroll
        for (int tnl = 0; tnl < 2; ++tnl) {
            int tn = w * 2 + tnl;
            bf16x8 bf2 = *(const bf16x8*)(wf2frag + (((tn * 4 + ks) * 64) + lane) * 8);
#pragma unroll
            for (int tm = 0; tm < 4; ++tm)
                acc[tm][tnl] = __builtin_amdgcn_mfma_f32_16x16x32_bf16(a4[tm], bf2, acc[tm][tnl], 0, 0, 0);
        }
    }

    // ---- step C: agg[f] = sum_n W[n][f] * mask[n] * y[b, nbh[n], f] ----
    float aggv0 = 0.f, aggv1 = 0.f;
    const unsigned short* yb = ybf + (size_t)bidx * NA * NF;
#pragma unroll
    for (int tm = 0; tm < 4; ++tm) {
        f32x4 m4 = *(const f32x4*)(smask + tm * 16 + g * 4);
        int4  nb4 = *(const int4*)(snbh + tm * 16 + g * 4);
#pragma unroll
        for (int r = 0; r < 4; ++r) {
            int yrow = (r == 0) ? nb4.x : (r == 1) ? nb4.y : (r == 2) ? nb4.z : nb4.w;
            const unsigned short* yp = yb + (size_t)yrow * NF + fc0;
            float y0 = bf2f(yp[0]);
            float y1 = bf2f(yp[16]);
            aggv0 = fmaf(acc[tm][0][r] * m4[r], y0, aggv0);
            aggv1 = fmaf(acc[tm][1][r] * m4[r], y1, aggv1);
        }
    }
    aggv0 += __shfl_xor(aggv0, 16); aggv1 += __shfl_xor(aggv1, 16);
    aggv0 += __shfl_xor(aggv0, 32); aggv1 += __shfl_xor(aggv1, 32);
    if (lane < 16) {
        float* ap = agg + (size_t)atom * NF + fbase;
        ap[lane] = aggv0;
        ap[16 + lane] = aggv1;
    }
}

// out = ssp(agg @ W_out + b_out), rows = 8192, BM=32 (256 blocks)
__global__ __launch_bounds__(256) void k_out(
    const float* __restrict__ agg, const unsigned short* __restrict__ frag,
    const float* __restrict__ bout, float* __restrict__ out)
{
    const unsigned short* wofrag = frag + FRAG_WOUT;
    const int lane = threadIdx.x & 63, w = threadIdx.x >> 6;
    const int rowbase = blockIdx.x * 32;
    const int f0 = w * 32 + (lane & 15);
    const float bo0 = bout[f0], bo1 = bout[f0 + 16];
    f32x4 acc[2][2];
    acc[0][0] = f32x4{bo0, bo0, bo0, bo0};
    acc[1][0] = f32x4{bo0, bo0, bo0, bo0};
    acc[0][1] = f32x4{bo1, bo1, bo1, bo1};
    acc[1][1] = f32x4{bo1, bo1, bo1, bo1};
#pragma unroll
    for (int ks = 0; ks < 4; ++ks) {
        bf16x8 a[2];
#pragma unroll
        for (int tm = 0; tm < 2; ++tm) {
            int row = rowbase + tm * 16 + (lane & 15);
            int k0  = ks * 32 + (lane >> 4) * 8;
            const float* p = agg + (size_t)row * NF + k0;
            float4 v0 = *(const float4*)p;
            float4 v1 = *(const float4*)(p + 4);
            bf16x8 t;
            t[0] = (short)f2bf(v0.x); t[1] = (short)f2bf(v0.y);
            t[2] = (short)f2bf(v0.z); t[3] = (short)f2bf(v0.w);
            t[4] = (short)f2bf(v1.x); t[5] = (short)f2bf(v1.y);
            t[6] = (short)f2bf(v1.z); t[7] = (short)f2bf(v1.w);
            a[tm] = t;
        }
#pragma unroll
        for (int tn = 0; tn < 2; ++tn) {
            bf16x8 bfr = *(const bf16x8*)(wofrag + ((((w * 2 + tn) * 4 + ks) * 64) + lane) * 8);
#pragma unroll
            for (int tm = 0; tm < 2; ++tm)
                acc[tm][tn] = __builtin_amdgcn_mfma_f32_16x16x32_bf16(a[tm], bfr, acc[tm][tn], 0, 0, 0);
        }
    }
    float lg2 = LOG2EF;
#pragma unroll
    for (int tm = 0; tm < 2; ++tm)
#pragma unroll
        for (int tn = 0; tn < 2; ++tn)
#pragma unroll
            for (int r = 0; r < 4; ++r) {
                int row = rowbase + tm * 16 + (lane >> 4) * 4 + r;
                int f   = w * 32 + tn * 16 + (lane & 15);
                out[(size_t)row * NF + f] = ssp2(acc[tm][tn][r] * lg2);
            }
}

extern "C" void kernel_launch(void* const* d_in, const int* in_sizes, int n_in,
                              void* d_out, int out_size, void* d_ws, size_t ws_size,
                              hipStream_t stream)
{
    (void)in_sizes; (void)n_in; (void)out_size; (void)ws_size;
    const float* x    = (const float*)d_in[0];
    // d_in[1] = r_ij (unused by reference)
    const float* fij  = (const float*)d_in[2];
    const int*   nbh  = (const int*)d_in[3];
    const float* mask = (const float*)d_in[4];
    const float* Win  = (const float*)d_in[5];
    const float* Wf1  = (const float*)d_in[6];
    const float* b1   = (const float*)d_in[7];
    const float* Wf2  = (const float*)d_in[8];
    const float* b2   = (const float*)d_in[9];
    const float* Wout = (const float*)d_in[10];
    const float* bout = (const float*)d_in[11];
    float* out = (float*)d_out;

    // ws layout: [0,106496) frags (53248 ushorts) | [106496, +2MB) y bf16 | [2203648, +4MB) agg f32
    unsigned short* frag = (unsigned short*)d_ws;
    unsigned short* ybf  = (unsigned short*)((char*)d_ws + 106496);
    float*          agg  = (float*)((char*)d_ws + 2203648);

    k_prep  <<<208,  256, 0, stream>>>(Wf1, Wf2, Win, Wout, frag);
    k_in2f  <<<256,  256, 0, stream>>>(x, frag, ybf);
    k_cfconv<<<8192, 256, 0, stream>>>(fij, nbh, mask, b1, b2, frag, ybf, agg);
    k_out   <<<256,  256, 0, stream>>>(agg, frag, bout, out);
}